// Round 4
// baseline (227.208 us; speedup 1.0000x reference)
//
#include <hip/hip_runtime.h>
#include <hip/hip_cooperative_groups.h>

namespace cg = cooperative_groups;

#define NB_     32
#define NSITES_ 65536
#define NNGB_   13
#define DIM_    3
#define NG_     48
#define GD_     (NG_ * DIM_)   // 144

typedef unsigned uvec4_t __attribute__((ext_vector_type(4)));

// ---------------------------------------------------------------------------
// Fused cooperative kernel. 1024 blocks x 256 threads, 4 blocks/CU.
// Phase 1: each block transposes 64 sites of In (f32, batch-major) into
//          InT (bf16, site-major, 64 B/site). Blocks 0..38 also each compute
//          one Wmean entry.
// grid.sync()
// Phase 2: gather-conv. thread = (site, quarter): 4 lanes cover one site's
//          64-B InT row; 8 batches x 3 dims accumulators per thread.
// ---------------------------------------------------------------------------
__global__ __launch_bounds__(256, 4) void fused_kernel_78486(
    const float* __restrict__ In,
    const float* __restrict__ wtVC,
    const float* __restrict__ gdiags,
    const int*   __restrict__ perms,
    const int*   __restrict__ nn,
    float*  __restrict__ wm,
    ushort* __restrict__ InT,
    float*  __restrict__ out)
{
    const int t   = threadIdx.x;
    const int blk = blockIdx.x;            // 0..1023

    __shared__ ushort tile[64][40];        // padded transpose tile
    __shared__ float  wpj[GD_];
    __shared__ float  red[4];
    __shared__ float  ws[DIM_ * NNGB_];

    // ---- Phase 1a: transpose 64 sites ----
    const int s0 = blk * 64;
    const int sl = t & 63, bq = t >> 6;
#pragma unroll
    for (int r = 0; r < 8; r++) {
        int b = bq * 8 + r;
        float v = In[b * NSITES_ + s0 + sl];
        unsigned fu = __float_as_uint(v);
        fu = fu + 0x7FFFu + ((fu >> 16) & 1u);   // RNE f32->bf16
        tile[sl][b] = (ushort)(fu >> 16);
    }
    __syncthreads();
    {
        const int site = t >> 2, q = t & 3;
        uvec4_t val = *(const uvec4_t*)&tile[site][q * 8];
        *(uvec4_t*)(InT + (size_t)(s0 + site) * NB_ + q * 8) = val;
    }

    // ---- Phase 1b: Wmean entry for blocks 0..38 ----
    if (blk < DIM_ * NNGB_) {
        const int d = blk / NNGB_, j = blk - NNGB_ * d;
        if (t < GD_) {
            int g = t / DIM_, dp = t - DIM_ * g;
            wpj[t] = wtVC[dp * NNGB_ + perms[g * NNGB_ + j]];
        }
        __syncthreads();
        float acc = 0.f;
        for (int e = t; e < NG_ * GD_; e += 256) {
            int g = e / GD_;
            int k = e - g * GD_;
            acc += gdiags[(g * DIM_ + d) * GD_ + k] * wpj[k];
        }
#pragma unroll
        for (int off = 32; off > 0; off >>= 1) acc += __shfl_down(acc, off, 64);
        if ((t & 63) == 0) red[t >> 6] = acc;
        __syncthreads();
        if (t == 0) wm[blk] = (red[0] + red[1] + red[2] + red[3]) * (1.0f / NG_);
    }

    // ---- grid-wide barrier: InT + wm complete ----
    cg::this_grid().sync();

    // ---- Phase 2: gather-conv ----
    if (t < DIM_ * NNGB_) ws[t] = wm[t];
    __syncthreads();

    const int s = blk * 64 + (t >> 2);
    const int q = t & 3;

    float a0[8], a1[8], a2[8];
#pragma unroll
    for (int i = 0; i < 8; i++) { a0[i] = 0.f; a1[i] = 0.f; a2[i] = 0.f; }

#pragma unroll
    for (int j = 0; j < NNGB_; j++) {
        int idx = nn[j * NSITES_ + s];
        uvec4_t u = *(const uvec4_t*)(InT + ((size_t)idx << 5) + (q << 3));
        unsigned uu[4] = {u.x, u.y, u.z, u.w};
        float v[8];
#pragma unroll
        for (int k = 0; k < 4; k++) {
            v[2 * k]     = __uint_as_float(uu[k] << 16);
            v[2 * k + 1] = __uint_as_float(uu[k] & 0xFFFF0000u);
        }
        float w0 = ws[j], w1 = ws[NNGB_ + j], w2 = ws[2 * NNGB_ + j];
#pragma unroll
        for (int i = 0; i < 8; i++) {
            a0[i] += w0 * v[i];
            a1[i] += w1 * v[i];
            a2[i] += w2 * v[i];
        }
    }

#pragma unroll
    for (int i = 0; i < 8; i++) {
        int b = q * 8 + i;
        size_t base = (size_t)b * DIM_ * NSITES_ + s;
        out[base]               = a0[i];
        out[base + NSITES_]     = a1[i];
        out[base + 2 * NSITES_] = a2[i];
    }
}

// ---------------------------------------------------------------------------
// Fallback path (round-2 structure): prep + gather as two launches.
// ---------------------------------------------------------------------------
__global__ __launch_bounds__(256) void prep_kernel_78486(
    const float* __restrict__ In,
    const float* __restrict__ wtVC,
    const float* __restrict__ gdiags,
    const int*   __restrict__ perms,
    float*  __restrict__ wm,
    ushort* __restrict__ InT,
    int nTransBlocks)
{
    const int t = threadIdx.x;
    if ((int)blockIdx.x < DIM_ * NNGB_) {
        const int p = blockIdx.x;
        const int d = p / NNGB_, j = p - NNGB_ * d;
        __shared__ float wpj[GD_];
        __shared__ float red[4];
        if (t < GD_) {
            int g = t / DIM_, dp = t - DIM_ * g;
            wpj[t] = wtVC[dp * NNGB_ + perms[g * NNGB_ + j]];
        }
        __syncthreads();
        float acc = 0.f;
        for (int e = t; e < NG_ * GD_; e += 256) {
            int g = e / GD_;
            int k = e - g * GD_;
            acc += gdiags[(g * DIM_ + d) * GD_ + k] * wpj[k];
        }
#pragma unroll
        for (int off = 32; off > 0; off >>= 1) acc += __shfl_down(acc, off, 64);
        if ((t & 63) == 0) red[t >> 6] = acc;
        __syncthreads();
        if (t == 0) wm[p] = (red[0] + red[1] + red[2] + red[3]) * (1.0f / NG_);
    } else {
        const int tb = blockIdx.x - DIM_ * NNGB_;
        if (tb >= nTransBlocks) return;
        const int s0 = tb * 64;
        __shared__ ushort tile[64][40];
        const int sl = t & 63, bq = t >> 6;
#pragma unroll
        for (int r = 0; r < 8; r++) {
            int b = bq * 8 + r;
            float v = In[b * NSITES_ + s0 + sl];
            unsigned fu = __float_as_uint(v);
            fu = fu + 0x7FFFu + ((fu >> 16) & 1u);
            tile[sl][b] = (ushort)(fu >> 16);
        }
        __syncthreads();
        const int site = t >> 2, q = t & 3;
        uvec4_t val = *(const uvec4_t*)&tile[site][q * 8];
        *(uvec4_t*)(InT + (size_t)(s0 + site) * NB_ + q * 8) = val;
    }
}

__global__ __launch_bounds__(256) void gather_kernel_78486(
    const ushort* __restrict__ InT,
    const int*    __restrict__ nn,
    const float*  __restrict__ wm,
    float* __restrict__ out)
{
    const int t = blockIdx.x * 256 + threadIdx.x;
    const int q = t & 3;
    const int s = t >> 2;

    __shared__ float ws[DIM_ * NNGB_];
    if (threadIdx.x < DIM_ * NNGB_) ws[threadIdx.x] = wm[threadIdx.x];
    __syncthreads();

    float a0[8], a1[8], a2[8];
#pragma unroll
    for (int i = 0; i < 8; i++) { a0[i] = 0.f; a1[i] = 0.f; a2[i] = 0.f; }

#pragma unroll
    for (int j = 0; j < NNGB_; j++) {
        int idx = nn[j * NSITES_ + s];
        uvec4_t u = *(const uvec4_t*)(InT + ((size_t)idx << 5) + (q << 3));
        unsigned uu[4] = {u.x, u.y, u.z, u.w};
        float v[8];
#pragma unroll
        for (int k = 0; k < 4; k++) {
            v[2 * k]     = __uint_as_float(uu[k] << 16);
            v[2 * k + 1] = __uint_as_float(uu[k] & 0xFFFF0000u);
        }
        float w0 = ws[j], w1 = ws[NNGB_ + j], w2 = ws[2 * NNGB_ + j];
#pragma unroll
        for (int i = 0; i < 8; i++) {
            a0[i] += w0 * v[i];
            a1[i] += w1 * v[i];
            a2[i] += w2 * v[i];
        }
    }

#pragma unroll
    for (int i = 0; i < 8; i++) {
        int b = q * 8 + i;
        size_t base = (size_t)b * DIM_ * NSITES_ + s;
        out[base]               = a0[i];
        out[base + NSITES_]     = a1[i];
        out[base + 2 * NSITES_] = a2[i];
    }
}

__global__ __launch_bounds__(256) void gather_fallback_78486(
    const float* __restrict__ In,
    const int*   __restrict__ nn,
    const float* __restrict__ wm,
    float* __restrict__ out)
{
    const int t = blockIdx.x * 256 + threadIdx.x;
    const int s = t & (NSITES_ - 1);
    const int b = t >> 16;
    float x0 = 0.f, x1 = 0.f, x2 = 0.f;
#pragma unroll
    for (int j = 0; j < NNGB_; j++) {
        int idx = nn[j * NSITES_ + s];
        float v = In[b * NSITES_ + idx];
        x0 += wm[0 * NNGB_ + j] * v;
        x1 += wm[1 * NNGB_ + j] * v;
        x2 += wm[2 * NNGB_ + j] * v;
    }
    out[(b * DIM_ + 0) * NSITES_ + s] = x0;
    out[(b * DIM_ + 1) * NSITES_ + s] = x1;
    out[(b * DIM_ + 2) * NSITES_ + s] = x2;
}

extern "C" void kernel_launch(void* const* d_in, const int* in_sizes, int n_in,
                              void* d_out, int out_size, void* d_ws, size_t ws_size,
                              hipStream_t stream)
{
    const float* In     = (const float*)d_in[0];
    const float* wtVC   = (const float*)d_in[1];
    const float* gdiags = (const float*)d_in[2];
    const int*   perms  = (const int*)d_in[3];
    const int*   nn     = (const int*)d_in[4];
    float* out = (float*)d_out;

    float*  wm  = (float*)d_ws;
    ushort* InT = (ushort*)((char*)d_ws + 1024);

    const size_t need = 1024 + (size_t)NSITES_ * NB_ * sizeof(ushort);
    const int nTrans = NSITES_ / 64;   // 1024

    if (ws_size >= need) {
        void* args[] = {(void*)&In, (void*)&wtVC, (void*)&gdiags, (void*)&perms,
                        (void*)&nn, (void*)&wm, (void*)&InT, (void*)&out};
        hipError_t e = hipLaunchCooperativeKernel(
            (const void*)fused_kernel_78486, dim3(nTrans), dim3(256),
            args, 0, stream);
        if (e != hipSuccess) {
            // Deterministic fallback: two-launch round-2 path.
            prep_kernel_78486<<<DIM_ * NNGB_ + nTrans, 256, 0, stream>>>(
                In, wtVC, gdiags, perms, wm, InT, nTrans);
            gather_kernel_78486<<<(NSITES_ * 4) / 256, 256, 0, stream>>>(
                InT, nn, wm, out);
        }
    } else {
        prep_kernel_78486<<<DIM_ * NNGB_, 256, 0, stream>>>(
            In, wtVC, gdiags, perms, wm, (ushort*)nullptr, 0);
        gather_fallback_78486<<<(NSITES_ * NB_) / 256, 256, 0, stream>>>(
            In, nn, wm, out);
    }
}

// Round 5
// 92.912 us; speedup vs baseline: 2.4454x; 2.4454x over previous
//
#include <hip/hip_runtime.h>

#define NB_     32
#define NSITES_ 65536
#define NNGB_   13
#define DIM_    3
#define NG_     48
#define GD_     (NG_ * DIM_)   // 144

typedef unsigned uvec4_t __attribute__((ext_vector_type(4)));

// ---------------------------------------------------------------------------
// Kernel A (fused):
//   blocks [0, 39):   one Wmean entry per block.
//   blocks [39, ...): transpose In (32,65536) f32 -> InT (65536,32) bf16.
// ---------------------------------------------------------------------------
__global__ __launch_bounds__(256) void prep_kernel_78486(
    const float* __restrict__ In,
    const float* __restrict__ wtVC,
    const float* __restrict__ gdiags,
    const int*   __restrict__ perms,
    float*  __restrict__ wm,      // 39 floats
    ushort* __restrict__ InT,     // 65536*32 bf16 (may be null in fallback)
    int nTransBlocks)
{
    const int t = threadIdx.x;
    if ((int)blockIdx.x < DIM_ * NNGB_) {
        const int p = blockIdx.x;
        const int d = p / NNGB_, j = p - NNGB_ * d;
        __shared__ float wpj[GD_];
        __shared__ float red[4];
        if (t < GD_) {
            int g = t / DIM_, dp = t - DIM_ * g;   // k = g*3+dp = t
            wpj[t] = wtVC[dp * NNGB_ + perms[g * NNGB_ + j]];
        }
        __syncthreads();
        float acc = 0.f;
        for (int e = t; e < NG_ * GD_; e += 256) {   // coalesced over k
            int g = e / GD_;
            int k = e - g * GD_;
            acc += gdiags[(g * DIM_ + d) * GD_ + k] * wpj[k];
        }
#pragma unroll
        for (int off = 32; off > 0; off >>= 1) acc += __shfl_down(acc, off, 64);
        if ((t & 63) == 0) red[t >> 6] = acc;
        __syncthreads();
        if (t == 0) wm[p] = (red[0] + red[1] + red[2] + red[3]) * (1.0f / NG_);
    } else {
        const int tb = blockIdx.x - DIM_ * NNGB_;
        if (tb >= nTransBlocks) return;
        const int s0 = tb * 64;
        __shared__ ushort tile[64][40];   // 80-B rows: 16-B aligned reads
        const int sl = t & 63, bq = t >> 6;
#pragma unroll
        for (int r = 0; r < 8; r++) {
            int b = bq * 8 + r;
            float v = In[b * NSITES_ + s0 + sl];
            unsigned fu = __float_as_uint(v);
            fu = fu + 0x7FFFu + ((fu >> 16) & 1u);   // RNE f32->bf16
            tile[sl][b] = (ushort)(fu >> 16);
        }
        __syncthreads();
        const int site = t >> 2, q = t & 3;          // 64 sites x 4 quads
        uvec4_t val = *(const uvec4_t*)&tile[site][q * 8];
        *(uvec4_t*)(InT + (size_t)(s0 + site) * NB_ + q * 8) = val;
    }
}

// ---------------------------------------------------------------------------
// Kernel B: gather-conv, MLP-maximized.
// thread = (site, quarter): 4 lanes cover one site's 64-B InT row; each
// thread handles 8 batches x 3 dims = 24 accumulators.
// All 13 index loads issue first, then all 13 independent 16-B table loads
// (208 B/lane outstanding), then the FMA reduction — hides L2/L3 latency.
// Weights read via wave-uniform scalar loads (no LDS, no barrier).
// ---------------------------------------------------------------------------
__global__ __launch_bounds__(256) void gather_kernel_78486(
    const ushort* __restrict__ InT,
    const int*    __restrict__ nn,    // (13, 65536)
    const float*  __restrict__ wm,    // 39
    float* __restrict__ out)          // (32, 3, 65536)
{
    const int t = blockIdx.x * 256 + threadIdx.x;   // 0..262143
    const int q = t & 3;                            // batch quarter
    const int s = t >> 2;                           // site

    // Stage 1: all 13 indices in flight.
    int idx[NNGB_];
#pragma unroll
    for (int j = 0; j < NNGB_; j++) idx[j] = nn[j * NSITES_ + s];

    // Stage 2: all 13 gathers in flight.
    uvec4_t u[NNGB_];
#pragma unroll
    for (int j = 0; j < NNGB_; j++)
        u[j] = *(const uvec4_t*)(InT + ((size_t)idx[j] << 5) + (q << 3));

    // Stage 3: accumulate. wm[*] are wave-uniform -> scalar loads.
    float a0[8], a1[8], a2[8];
#pragma unroll
    for (int i = 0; i < 8; i++) { a0[i] = 0.f; a1[i] = 0.f; a2[i] = 0.f; }

#pragma unroll
    for (int j = 0; j < NNGB_; j++) {
        unsigned uu[4] = {u[j].x, u[j].y, u[j].z, u[j].w};
        float v[8];
#pragma unroll
        for (int k = 0; k < 4; k++) {
            v[2 * k]     = __uint_as_float(uu[k] << 16);
            v[2 * k + 1] = __uint_as_float(uu[k] & 0xFFFF0000u);
        }
        float w0 = wm[j], w1 = wm[NNGB_ + j], w2 = wm[2 * NNGB_ + j];
#pragma unroll
        for (int i = 0; i < 8; i++) {
            a0[i] += w0 * v[i];
            a1[i] += w1 * v[i];
            a2[i] += w2 * v[i];
        }
    }

#pragma unroll
    for (int i = 0; i < 8; i++) {
        int b = q * 8 + i;
        size_t base = (size_t)b * DIM_ * NSITES_ + s;
        out[base]               = a0[i];
        out[base + NSITES_]     = a1[i];
        out[base + 2 * NSITES_] = a2[i];
    }
}

// ---------------------------------------------------------------------------
// Fallback (tiny ws): direct gather from batch-major In fp32.
// ---------------------------------------------------------------------------
__global__ __launch_bounds__(256) void gather_fallback_78486(
    const float* __restrict__ In,
    const int*   __restrict__ nn,
    const float* __restrict__ wm,
    float* __restrict__ out)
{
    const int t = blockIdx.x * 256 + threadIdx.x;
    const int s = t & (NSITES_ - 1);
    const int b = t >> 16;
    float x0 = 0.f, x1 = 0.f, x2 = 0.f;
#pragma unroll
    for (int j = 0; j < NNGB_; j++) {
        int idx = nn[j * NSITES_ + s];
        float v = In[b * NSITES_ + idx];
        x0 += wm[0 * NNGB_ + j] * v;
        x1 += wm[1 * NNGB_ + j] * v;
        x2 += wm[2 * NNGB_ + j] * v;
    }
    out[(b * DIM_ + 0) * NSITES_ + s] = x0;
    out[(b * DIM_ + 1) * NSITES_ + s] = x1;
    out[(b * DIM_ + 2) * NSITES_ + s] = x2;
}

extern "C" void kernel_launch(void* const* d_in, const int* in_sizes, int n_in,
                              void* d_out, int out_size, void* d_ws, size_t ws_size,
                              hipStream_t stream)
{
    const float* In     = (const float*)d_in[0];   // (32,1,65536) f32
    const float* wtVC   = (const float*)d_in[1];   // (3,13) f32
    const float* gdiags = (const float*)d_in[2];   // (144,144) f32
    const int*   perms  = (const int*)d_in[3];     // (48,13) i32
    const int*   nn     = (const int*)d_in[4];     // (13,65536) i32
    float* out = (float*)d_out;

    float*  wm  = (float*)d_ws;                          // 39 floats
    ushort* InT = (ushort*)((char*)d_ws + 1024);         // 4 MB bf16

    const size_t need = 1024 + (size_t)NSITES_ * NB_ * sizeof(ushort);
    const int nTrans = NSITES_ / 64;                     // 1024

    if (ws_size >= need) {
        prep_kernel_78486<<<DIM_ * NNGB_ + nTrans, 256, 0, stream>>>(
            In, wtVC, gdiags, perms, wm, InT, nTrans);
        gather_kernel_78486<<<(NSITES_ * 4) / 256, 256, 0, stream>>>(
            InT, nn, wm, out);
    } else {
        prep_kernel_78486<<<DIM_ * NNGB_, 256, 0, stream>>>(
            In, wtVC, gdiags, perms, wm, (ushort*)nullptr, 0);
        gather_fallback_78486<<<(NSITES_ * NB_) / 256, 256, 0, stream>>>(
            In, nn, wm, out);
    }
}